// Round 1
// baseline (4259.014 us; speedup 1.0000x reference)
//
#include <hip/hip_runtime.h>
#include <math.h>

// GCN 2-layer forward on MI355X.
// N=100000, E=1600000, DIN=512, DH=128, DOUT=40 (sizes derived at runtime).
//
// Pipeline:
//   deg -> dinv -> norm[e]
//   h   = x @ W1                       (gemm1, fp32 tiled)
//   agg1= selfinit(h*dinv^2) + edge atomics (h[src]*norm -> agg1[dst])
//   h1  = relu(agg1 + b1)              (in place)
//   g   = h1 @ W2                      (gemm2; g reuses h's buffer)
//   out1= selfinit(g*dinv^2) + edge atomics   (agg2 lives in d_out)
//   out1+= b2 ; out2 = log_softmax(out1)      (finalize)

__global__ void k_init_deg(float* __restrict__ deg, int n) {
    int i = blockIdx.x * blockDim.x + threadIdx.x;
    if (i < n) deg[i] = 1.0f;   // self-loop
}

__global__ void k_count_deg(const int* __restrict__ dst, float* __restrict__ deg, int e) {
    int i = blockIdx.x * blockDim.x + threadIdx.x;
    if (i < e) atomicAdd(&deg[dst[i]], 1.0f);
}

__global__ void k_dinv(float* __restrict__ deg, int n) {
    int i = blockIdx.x * blockDim.x + threadIdx.x;
    if (i < n) deg[i] = rsqrtf(deg[i]);   // deg >= 1 always (self-loop)
}

__global__ void k_norm(const int* __restrict__ src, const int* __restrict__ dst,
                       const float* __restrict__ dinv, float* __restrict__ norm, int e) {
    int i = blockIdx.x * blockDim.x + threadIdx.x;
    if (i < e) norm[i] = dinv[src[i]] * dinv[dst[i]];
}

// ---- GEMM1: x[n,512] @ W1[512,128] -> h[n,128] --------------------------
// 256 threads, 32 rows/block. LDS: xs 8KB + ws 32KB = 40KB -> 4 blocks/CU.
// Each thread: 4 rows x 4 cols register tile, float4 LDS reads.
__global__ __launch_bounds__(256) void k_gemm1(const float* __restrict__ x,
                                               const float* __restrict__ W1,
                                               float* __restrict__ h, int n) {
    __shared__ float xs[32][64];
    __shared__ float ws[64][128];
    const int tid  = threadIdx.x;
    const int row0 = blockIdx.x * 32;
    const int c4   = (tid & 31) * 4;   // col base 0..124
    const int rg   = tid >> 5;         // 0..7 -> rows rg*4..rg*4+3
    float4 acc[4];
    for (int r = 0; r < 4; r++) acc[r] = make_float4(0.f, 0.f, 0.f, 0.f);

    for (int kb = 0; kb < 512; kb += 64) {
        // stage xs: 32x64 floats = 512 float4
        for (int t = tid; t < 512; t += 256) {
            int r = t >> 4;
            int kk = (t & 15) * 4;
            int grow = row0 + r;
            float4 v = make_float4(0.f, 0.f, 0.f, 0.f);
            if (grow < n) v = *(const float4*)&x[(size_t)grow * 512 + kb + kk];
            *(float4*)&xs[r][kk] = v;
        }
        // stage ws: 64x128 floats = 2048 float4
        for (int t = tid; t < 2048; t += 256) {
            int kk = t >> 5;
            int cc = (t & 31) * 4;
            *(float4*)&ws[kk][cc] = *(const float4*)&W1[(size_t)(kb + kk) * 128 + cc];
        }
        __syncthreads();
        for (int k = 0; k < 64; k += 4) {
            float4 xv[4], wv[4];
#pragma unroll
            for (int r = 0; r < 4; r++) xv[r] = *(const float4*)&xs[rg * 4 + r][k];
#pragma unroll
            for (int j = 0; j < 4; j++) wv[j] = *(const float4*)&ws[k + j][c4];
#pragma unroll
            for (int j = 0; j < 4; j++) {
                float4 w = wv[j];
#pragma unroll
                for (int r = 0; r < 4; r++) {
                    float xr = (&xv[r].x)[j];
                    acc[r].x += xr * w.x;
                    acc[r].y += xr * w.y;
                    acc[r].z += xr * w.z;
                    acc[r].w += xr * w.w;
                }
            }
        }
        __syncthreads();
    }
    for (int r = 0; r < 4; r++) {
        int grow = row0 + rg * 4 + r;
        if (grow < n) *(float4*)&h[(size_t)grow * 128 + c4] = acc[r];
    }
}

// ---- self-loop init: agg[i][c] = hin[i][c] * dinv[i]^2 ------------------
template <int D>
__global__ void k_selfinit(const float* __restrict__ hin, const float* __restrict__ dinv,
                           float* __restrict__ agg, long long total) {
    long long idx = (long long)blockIdx.x * blockDim.x + threadIdx.x;
    if (idx >= total) return;
    int i = (int)(idx / D);
    float d = dinv[i];
    agg[idx] = hin[idx] * d * d;
}

// ---- edge aggregation: agg[dst] += hin[src] * norm ----------------------
// D/4 threads per edge, float4 gather + 4 scalar atomics.
template <int D>
__global__ void k_edge_agg(const int* __restrict__ src, const int* __restrict__ dst,
                           const float* __restrict__ norm, const float* __restrict__ hin,
                           float* __restrict__ agg, int e) {
    constexpr int TPE = D / 4;
    long long idx = (long long)blockIdx.x * blockDim.x + threadIdx.x;
    if (idx >= (long long)e * TPE) return;
    int eid = (int)(idx / TPE);
    int q   = (int)(idx % TPE);
    int c   = q * 4;
    int s = src[eid], t = dst[eid];
    float w = norm[eid];
    float4 v = *(const float4*)&hin[(size_t)s * D + c];
    float* ap = &agg[(size_t)t * D + c];
    atomicAdd(ap + 0, v.x * w);
    atomicAdd(ap + 1, v.y * w);
    atomicAdd(ap + 2, v.z * w);
    atomicAdd(ap + 3, v.w * w);
}

__global__ void k_bias_relu(float* __restrict__ a, const float* __restrict__ b1, long long total) {
    long long idx = (long long)blockIdx.x * blockDim.x + threadIdx.x;
    if (idx >= total) return;
    int c = (int)(idx & 127);
    float v = a[idx] + b1[c];
    a[idx] = v > 0.f ? v : 0.f;
}

// ---- GEMM2: h1[n,128] @ W2[128,40] -> g[n,40] ---------------------------
// 320 threads (5 waves), 32 rows/block. LDS: hs ~16.9KB + ws 20KB.
__global__ __launch_bounds__(320) void k_gemm2(const float* __restrict__ h1,
                                               const float* __restrict__ W2,
                                               float* __restrict__ g, int n) {
    __shared__ float hs[32][132];   // pad 128->132 (float4-aligned, bank-safe)
    __shared__ float ws[128 * 40];
    const int tid  = threadIdx.x;
    const int row0 = blockIdx.x * 32;
    for (int t = tid; t < 5120; t += 320) ws[t] = W2[t];
    for (int t = tid; t < 1024; t += 320) {
        int r = t >> 5;
        int kk = (t & 31) * 4;
        int grow = row0 + r;
        float4 v = make_float4(0.f, 0.f, 0.f, 0.f);
        if (grow < n) v = *(const float4*)&h1[(size_t)grow * 128 + kk];
        *(float4*)&hs[r][kk] = v;
    }
    __syncthreads();
    const int c  = tid % 40;
    const int rg = tid / 40;   // 0..7
    float acc[4] = {0.f, 0.f, 0.f, 0.f};
    for (int k = 0; k < 128; k++) {
        float w = ws[k * 40 + c];
#pragma unroll
        for (int r = 0; r < 4; r++) acc[r] += hs[rg * 4 + r][k] * w;
    }
    for (int r = 0; r < 4; r++) {
        int grow = row0 + rg * 4 + r;
        if (grow < n) g[(size_t)grow * 40 + c] = acc[r];
    }
}

// ---- finalize: out1 += b2 (h2); out2 = log_softmax(h2) ------------------
__global__ __launch_bounds__(256) void k_finalize(float* __restrict__ out1,
                                                  float* __restrict__ out2,
                                                  const float* __restrict__ b2, int n) {
    __shared__ float s[32][41];
    __shared__ float mrow[32], lrow[32];
    const int row0 = blockIdx.x * 32;
    const int tid  = threadIdx.x;
    for (int t = tid; t < 1280; t += 256) {
        int r = t / 40, c = t % 40;
        int grow = row0 + r;
        float v = 0.f;
        if (grow < n) {
            v = out1[(size_t)grow * 40 + c] + b2[c];
            out1[(size_t)grow * 40 + c] = v;   // h2 output
        }
        s[r][c] = v;
    }
    __syncthreads();
    if (tid < 32) {
        float m = -1e30f;
        for (int k = 0; k < 40; k++) m = fmaxf(m, s[tid][k]);
        float sum = 0.f;
        for (int k = 0; k < 40; k++) sum += expf(s[tid][k] - m);
        mrow[tid] = m;
        lrow[tid] = logf(sum);
    }
    __syncthreads();
    for (int t = tid; t < 1280; t += 256) {
        int r = t / 40, c = t % 40;
        int grow = row0 + r;
        if (grow < n) out2[(size_t)grow * 40 + c] = s[r][c] - mrow[r] - lrow[r];
    }
}

extern "C" void kernel_launch(void* const* d_in, const int* in_sizes, int n_in,
                              void* d_out, int out_size, void* d_ws, size_t ws_size,
                              hipStream_t stream) {
    const float* x  = (const float*)d_in[0];
    const int*   ei = (const int*)d_in[1];
    const float* W1 = (const float*)d_in[2];
    const float* b1 = (const float*)d_in[3];
    const float* W2 = (const float*)d_in[4];
    const float* b2 = (const float*)d_in[5];

    const int n = in_sizes[0] / 512;
    const int e = in_sizes[1] / 2;
    const int* src = ei;
    const int* dst = ei + e;

    float* ws   = (float*)d_ws;
    float* dinv = ws;                         // [n]
    float* norm = dinv + n;                   // [e]
    float* h    = norm + e;                   // [n*128]; later reused as g [n*40]
    float* agg1 = h + (size_t)n * 128;        // [n*128] -> h1 in place
    float* g    = h;                          // reuse
    float* out1 = (float*)d_out;              // [n*40]  (agg2 accumulates here)
    float* out2 = out1 + (size_t)n * 40;      // [n*40]

    const int B = 256;
    // degree / norm
    k_init_deg<<<(n + B - 1) / B, B, 0, stream>>>(dinv, n);
    k_count_deg<<<(e + B - 1) / B, B, 0, stream>>>(dst, dinv, e);
    k_dinv<<<(n + B - 1) / B, B, 0, stream>>>(dinv, n);
    k_norm<<<(e + B - 1) / B, B, 0, stream>>>(src, dst, dinv, norm, e);

    // layer 1
    k_gemm1<<<(n + 31) / 32, 256, 0, stream>>>(x, W1, h, n);
    {
        long long total = (long long)n * 128;
        k_selfinit<128><<<(unsigned)((total + B - 1) / B), B, 0, stream>>>(h, dinv, agg1, total);
        long long tthreads = (long long)e * 32;
        k_edge_agg<128><<<(unsigned)((tthreads + B - 1) / B), B, 0, stream>>>(src, dst, norm, h, agg1, e);
        k_bias_relu<<<(unsigned)((total + B - 1) / B), B, 0, stream>>>(agg1, b1, total);
    }

    // layer 2
    k_gemm2<<<(n + 31) / 32, 320, 0, stream>>>(agg1, W2, g, n);
    {
        long long total = (long long)n * 40;
        k_selfinit<40><<<(unsigned)((total + B - 1) / B), B, 0, stream>>>(g, dinv, out1, total);
        long long tthreads = (long long)e * 10;
        k_edge_agg<40><<<(unsigned)((tthreads + B - 1) / B), B, 0, stream>>>(src, dst, norm, g, out1, e);
    }
    k_finalize<<<(n + 31) / 32, 256, 0, stream>>>(out1, out2, b2, n);
}

// Round 2
// 945.695 us; speedup vs baseline: 4.5036x; 4.5036x over previous
//
#include <hip/hip_runtime.h>
#include <math.h>

// GCN 2-layer forward on MI355X — round 2: CSR pull-mode aggregation
// (no fp32 atomics; counting-sort edges by dst, gather + single write).
//
// Pipeline:
//   cnt  = histogram(dst)               (int atomics)
//   row_ptr = exclusive_scan(cnt)       (3-pass scan)
//   dinv = rsqrt(cnt+1)
//   scatter: es_src[pos]=src, es_norm[pos]=dinv[src]*dinv[dst]  (int cursor atomics)
//   h    = x @ W1                       (gemm1, fp32 tiled)
//   h1   = relu( dinv^2*h[i] + sum_edges norm*h[src] + b1 )   (k_agg1, fused)
//   g    = h1 @ W2
//   out1 = dinv^2*g[i] + sum_edges norm*g[src] + b2           (k_agg2, fused)
//   out2 = log_softmax(out1)

// ---------------- CSR build ----------------------------------------------

__global__ void k_hist(const int* __restrict__ dst, int* __restrict__ cnt, int e) {
    int i = blockIdx.x * blockDim.x + threadIdx.x;
    if (i < e) atomicAdd(&cnt[dst[i]], 1);
}

__global__ void k_dinv(const int* __restrict__ cnt, float* __restrict__ dinv, int n) {
    int i = blockIdx.x * blockDim.x + threadIdx.x;
    if (i < n) dinv[i] = rsqrtf((float)(cnt[i] + 1));   // +1 self-loop
}

// scan pass 1: per-block (1024 elems) sums
__global__ __launch_bounds__(256) void k_scan1(const int* __restrict__ cnt, int* __restrict__ bsum, int n) {
    __shared__ int sd[256];
    int t = threadIdx.x;
    int base = blockIdx.x * 1024 + t * 4;
    int s = 0;
#pragma unroll
    for (int j = 0; j < 4; j++) { int i = base + j; if (i < n) s += cnt[i]; }
    sd[t] = s;
    __syncthreads();
    for (int d = 128; d > 0; d >>= 1) {
        if (t < d) sd[t] += sd[t + d];
        __syncthreads();
    }
    if (t == 0) bsum[blockIdx.x] = sd[0];
}

// scan pass 2: serial exclusive scan of block sums (nb ~ 98) + row_ptr[n]=e
__global__ void k_scan2(int* __restrict__ bsum, int nb, int* __restrict__ row_ptr, int n, int e) {
    if (threadIdx.x == 0 && blockIdx.x == 0) {
        int run = 0;
        for (int i = 0; i < nb; i++) { int v = bsum[i]; bsum[i] = run; run += v; }
        row_ptr[n] = e;
    }
}

// scan pass 3: per-block exclusive scan + base
__global__ __launch_bounds__(256) void k_scan3(const int* __restrict__ cnt, const int* __restrict__ bsum,
                                               int* __restrict__ row_ptr, int n) {
    __shared__ int sd[256];
    int t = threadIdx.x;
    int base = blockIdx.x * 1024 + t * 4;
    int v[4];
#pragma unroll
    for (int j = 0; j < 4; j++) { int i = base + j; v[j] = (i < n) ? cnt[i] : 0; }
    int s0 = v[0], s1 = s0 + v[1], s2 = s1 + v[2], s3 = s2 + v[3];
    sd[t] = s3;
    __syncthreads();
    // Hillis-Steele inclusive scan over 256 thread-totals
    for (int d = 1; d < 256; d <<= 1) {
        int x = (t >= d) ? sd[t - d] : 0;
        __syncthreads();
        sd[t] += x;
        __syncthreads();
    }
    int excl = sd[t] - s3;
    int off = bsum[blockIdx.x] + excl;
    if (base + 0 < n) row_ptr[base + 0] = off;
    if (base + 1 < n) row_ptr[base + 1] = off + s0;
    if (base + 2 < n) row_ptr[base + 2] = off + s1;
    if (base + 3 < n) row_ptr[base + 3] = off + s2;
}

__global__ void k_scatter(const int* __restrict__ src, const int* __restrict__ dst,
                          const float* __restrict__ dinv, int* __restrict__ cursor,
                          int* __restrict__ es_src, float* __restrict__ es_norm, int e) {
    int i = blockIdx.x * blockDim.x + threadIdx.x;
    if (i >= e) return;
    int s = src[i], d = dst[i];
    int pos = atomicAdd(&cursor[d], 1);
    es_src[pos] = s;
    es_norm[pos] = dinv[s] * dinv[d];
}

// ---- GEMM1: x[n,512] @ W1[512,128] -> h[n,128] --------------------------
__global__ __launch_bounds__(256) void k_gemm1(const float* __restrict__ x,
                                               const float* __restrict__ W1,
                                               float* __restrict__ h, int n) {
    __shared__ float xs[32][64];
    __shared__ float ws[64][128];
    const int tid  = threadIdx.x;
    const int row0 = blockIdx.x * 32;
    const int c4   = (tid & 31) * 4;
    const int rg   = tid >> 5;
    float4 acc[4];
    for (int r = 0; r < 4; r++) acc[r] = make_float4(0.f, 0.f, 0.f, 0.f);

    for (int kb = 0; kb < 512; kb += 64) {
        for (int t = tid; t < 512; t += 256) {
            int r = t >> 4;
            int kk = (t & 15) * 4;
            int grow = row0 + r;
            float4 v = make_float4(0.f, 0.f, 0.f, 0.f);
            if (grow < n) v = *(const float4*)&x[(size_t)grow * 512 + kb + kk];
            *(float4*)&xs[r][kk] = v;
        }
        for (int t = tid; t < 2048; t += 256) {
            int kk = t >> 5;
            int cc = (t & 31) * 4;
            *(float4*)&ws[kk][cc] = *(const float4*)&W1[(size_t)(kb + kk) * 128 + cc];
        }
        __syncthreads();
        for (int k = 0; k < 64; k += 4) {
            float4 xv[4], wv[4];
#pragma unroll
            for (int r = 0; r < 4; r++) xv[r] = *(const float4*)&xs[rg * 4 + r][k];
#pragma unroll
            for (int j = 0; j < 4; j++) wv[j] = *(const float4*)&ws[k + j][c4];
#pragma unroll
            for (int j = 0; j < 4; j++) {
                float4 w = wv[j];
#pragma unroll
                for (int r = 0; r < 4; r++) {
                    float xr = (&xv[r].x)[j];
                    acc[r].x += xr * w.x;
                    acc[r].y += xr * w.y;
                    acc[r].z += xr * w.z;
                    acc[r].w += xr * w.w;
                }
            }
        }
        __syncthreads();
    }
    for (int r = 0; r < 4; r++) {
        int grow = row0 + rg * 4 + r;
        if (grow < n) *(float4*)&h[(size_t)grow * 128 + c4] = acc[r];
    }
}

// ---- agg1: pull-mode, one wave per node, D=128 (float2/lane) + bias + relu
__global__ __launch_bounds__(256) void k_agg1(const float* __restrict__ h,
                                              const int* __restrict__ row_ptr,
                                              const int* __restrict__ es_src,
                                              const float* __restrict__ es_norm,
                                              const float* __restrict__ dinv,
                                              const float* __restrict__ b1,
                                              float* __restrict__ h1, int n) {
    const int tid  = threadIdx.x;
    const int node = blockIdx.x * 4 + (tid >> 6);
    if (node >= n) return;
    const int lane = tid & 63;
    const int c = lane * 2;
    const float di = dinv[node];
    float2 acc = *(const float2*)&h[(size_t)node * 128 + c];
    acc.x *= di * di;
    acc.y *= di * di;
    const int k0 = row_ptr[node], k1 = row_ptr[node + 1];
    for (int k = k0; k < k1; k++) {
        int s = es_src[k];
        float w = es_norm[k];
        float2 v = *(const float2*)&h[(size_t)s * 128 + c];
        acc.x += v.x * w;
        acc.y += v.y * w;
    }
    float2 bb = *(const float2*)&b1[c];
    acc.x += bb.x; acc.y += bb.y;
    acc.x = acc.x > 0.f ? acc.x : 0.f;
    acc.y = acc.y > 0.f ? acc.y : 0.f;
    *(float2*)&h1[(size_t)node * 128 + c] = acc;
}

// ---- GEMM2: h1[n,128] @ W2[128,40] -> g[n,40] ---------------------------
__global__ __launch_bounds__(320) void k_gemm2(const float* __restrict__ h1,
                                               const float* __restrict__ W2,
                                               float* __restrict__ g, int n) {
    __shared__ float hs[32][132];
    __shared__ float ws[128 * 40];
    const int tid  = threadIdx.x;
    const int row0 = blockIdx.x * 32;
    for (int t = tid; t < 5120; t += 320) ws[t] = W2[t];
    for (int t = tid; t < 1024; t += 320) {
        int r = t >> 5;
        int kk = (t & 31) * 4;
        int grow = row0 + r;
        float4 v = make_float4(0.f, 0.f, 0.f, 0.f);
        if (grow < n) v = *(const float4*)&h1[(size_t)grow * 128 + kk];
        *(float4*)&hs[r][kk] = v;
    }
    __syncthreads();
    const int c  = tid % 40;
    const int rg = tid / 40;
    float acc[4] = {0.f, 0.f, 0.f, 0.f};
    for (int k = 0; k < 128; k++) {
        float w = ws[k * 40 + c];
#pragma unroll
        for (int r = 0; r < 4; r++) acc[r] += hs[rg * 4 + r][k] * w;
    }
    for (int r = 0; r < 4; r++) {
        int grow = row0 + rg * 4 + r;
        if (grow < n) g[(size_t)grow * 40 + c] = acc[r];
    }
}

// ---- agg2: pull-mode, D=40, 6 nodes per 256-block, + b2 -----------------
__global__ __launch_bounds__(256) void k_agg2(const float* __restrict__ g,
                                              const int* __restrict__ row_ptr,
                                              const int* __restrict__ es_src,
                                              const float* __restrict__ es_norm,
                                              const float* __restrict__ dinv,
                                              const float* __restrict__ b2,
                                              float* __restrict__ out1, int n) {
    const int tid = threadIdx.x;
    if (tid >= 240) return;
    const int node = blockIdx.x * 6 + tid / 40;
    if (node >= n) return;
    const int c = tid % 40;
    const float di = dinv[node];
    float acc = g[(size_t)node * 40 + c] * di * di;
    const int k0 = row_ptr[node], k1 = row_ptr[node + 1];
    for (int k = k0; k < k1; k++) {
        int s = es_src[k];
        float w = es_norm[k];
        acc += g[(size_t)s * 40 + c] * w;
    }
    out1[(size_t)node * 40 + c] = acc + b2[c];
}

// ---- finalize: out2 = log_softmax(out1) ---------------------------------
__global__ __launch_bounds__(256) void k_finalize(const float* __restrict__ out1,
                                                  float* __restrict__ out2, int n) {
    __shared__ float s[32][41];
    __shared__ float mrow[32], lrow[32];
    const int row0 = blockIdx.x * 32;
    const int tid  = threadIdx.x;
    for (int t = tid; t < 1280; t += 256) {
        int r = t / 40, c = t % 40;
        int grow = row0 + r;
        float v = 0.f;
        if (grow < n) v = out1[(size_t)grow * 40 + c];
        s[r][c] = v;
    }
    __syncthreads();
    if (tid < 32) {
        float m = -1e30f;
        for (int k = 0; k < 40; k++) m = fmaxf(m, s[tid][k]);
        float sum = 0.f;
        for (int k = 0; k < 40; k++) sum += expf(s[tid][k] - m);
        mrow[tid] = m;
        lrow[tid] = logf(sum);
    }
    __syncthreads();
    for (int t = tid; t < 1280; t += 256) {
        int r = t / 40, c = t % 40;
        int grow = row0 + r;
        if (grow < n) out2[(size_t)grow * 40 + c] = s[r][c] - mrow[r] - lrow[r];
    }
}

static inline size_t align4(size_t v) { return (v + 3) & ~(size_t)3; }

extern "C" void kernel_launch(void* const* d_in, const int* in_sizes, int n_in,
                              void* d_out, int out_size, void* d_ws, size_t ws_size,
                              hipStream_t stream) {
    const float* x  = (const float*)d_in[0];
    const int*   ei = (const int*)d_in[1];
    const float* W1 = (const float*)d_in[2];
    const float* b1 = (const float*)d_in[3];
    const float* W2 = (const float*)d_in[4];
    const float* b2 = (const float*)d_in[5];

    const int n = in_sizes[0] / 512;
    const int e = in_sizes[1] / 2;
    const int* src = ei;
    const int* dst = ei + e;

    // workspace layout (all offsets multiple of 4 elements -> 16B aligned)
    char* p = (char*)d_ws;
    int*   cnt     = (int*)p;                 p += align4(n) * 4;
    int*   row_ptr = (int*)p;                 p += align4(n + 1) * 4;
    int*   cursor  = (int*)p;                 p += align4(n) * 4;
    float* dinv    = (float*)p;               p += align4(n) * 4;
    int*   es_src  = (int*)p;                 p += align4(e) * 4;
    float* es_norm = (float*)p;               p += align4(e) * 4;
    float* h       = (float*)p;               p += (size_t)n * 128 * 4;  // reused as g
    float* h1      = (float*)p;               p += (size_t)n * 128 * 4;
    float* g       = h;
    float* out1    = (float*)d_out;
    float* out2    = out1 + (size_t)n * 40;

    const int B = 256;
    const int nb = (n + 1023) / 1024;

    // CSR build
    hipMemsetAsync(cnt, 0, (size_t)n * 4, stream);
    k_hist<<<(e + B - 1) / B, B, 0, stream>>>(dst, cnt, e);
    k_dinv<<<(n + B - 1) / B, B, 0, stream>>>(cnt, dinv, n);
    k_scan1<<<nb, 256, 0, stream>>>(cnt, cursor /*reuse as bsum*/, n);
    k_scan2<<<1, 64, 0, stream>>>(cursor, nb, row_ptr, n, e);
    k_scan3<<<nb, 256, 0, stream>>>(cnt, cursor, row_ptr, n);
    hipMemcpyAsync(cursor, row_ptr, (size_t)n * 4, hipMemcpyDeviceToDevice, stream);
    k_scatter<<<(e + B - 1) / B, B, 0, stream>>>(src, dst, dinv, cursor, es_src, es_norm, e);

    // layer 1
    k_gemm1<<<(n + 31) / 32, 256, 0, stream>>>(x, W1, h, n);
    k_agg1<<<(n + 3) / 4, 256, 0, stream>>>(h, row_ptr, es_src, es_norm, dinv, b1, h1, n);

    // layer 2
    k_gemm2<<<(n + 31) / 32, 320, 0, stream>>>(h1, W2, g, n);
    k_agg2<<<(n + 5) / 6, 256, 0, stream>>>(g, row_ptr, es_src, es_norm, dinv, b2, out1, n);

    k_finalize<<<(n + 31) / 32, 256, 0, stream>>>(out1, out2, n);
}

// Round 3
// 785.856 us; speedup vs baseline: 5.4196x; 1.2034x over previous
//
#include <hip/hip_runtime.h>
#include <math.h>

// GCN 2-layer forward on MI355X — round 3: bf16 MFMA GEMM1 + bf16 hidden path.
//
//   CSR build (unchanged)
//   W1t  = bf16 transpose of W1                  [128][512]
//   h    = bf16( x @ W1 )                        (MFMA 16x16x32 bf16)
//   h1   = bf16( relu(dinv^2*h[i] + sum norm*h[src] + b1) )
//   g    = h1 @ W2                               (fp32 VALU, bf16 input)
//   out1 = dinv^2*g[i] + sum norm*g[src] + b2
//   out2 = log_softmax(out1)

typedef unsigned int uint;
typedef unsigned short ushort_t;
using short8  = __attribute__((ext_vector_type(8))) short;
using float4v = __attribute__((ext_vector_type(4))) float;

__device__ __forceinline__ ushort_t f2bf(float f) {
    uint u = __float_as_uint(f);
    u += 0x7FFFu + ((u >> 16) & 1u);   // RNE
    return (ushort_t)(u >> 16);
}
__device__ __forceinline__ float2 unpack2(uint v) {
    return make_float2(__uint_as_float(v << 16), __uint_as_float(v & 0xFFFF0000u));
}
__device__ __forceinline__ uint pack2(float a, float b) {
    return (uint)f2bf(a) | ((uint)f2bf(b) << 16);
}

// ---------------- CSR build ----------------------------------------------

__global__ void k_hist(const int* __restrict__ dst, int* __restrict__ cnt, int e) {
    int i = blockIdx.x * blockDim.x + threadIdx.x;
    if (i < e) atomicAdd(&cnt[dst[i]], 1);
}

__global__ void k_dinv(const int* __restrict__ cnt, float* __restrict__ dinv, int n) {
    int i = blockIdx.x * blockDim.x + threadIdx.x;
    if (i < n) dinv[i] = rsqrtf((float)(cnt[i] + 1));
}

__global__ __launch_bounds__(256) void k_scan1(const int* __restrict__ cnt, int* __restrict__ bsum, int n) {
    __shared__ int sd[256];
    int t = threadIdx.x;
    int base = blockIdx.x * 1024 + t * 4;
    int s = 0;
#pragma unroll
    for (int j = 0; j < 4; j++) { int i = base + j; if (i < n) s += cnt[i]; }
    sd[t] = s;
    __syncthreads();
    for (int d = 128; d > 0; d >>= 1) {
        if (t < d) sd[t] += sd[t + d];
        __syncthreads();
    }
    if (t == 0) bsum[blockIdx.x] = sd[0];
}

__global__ void k_scan2(int* __restrict__ bsum, int nb, int* __restrict__ row_ptr, int n, int e) {
    if (threadIdx.x == 0 && blockIdx.x == 0) {
        int run = 0;
        for (int i = 0; i < nb; i++) { int v = bsum[i]; bsum[i] = run; run += v; }
        row_ptr[n] = e;
    }
}

__global__ __launch_bounds__(256) void k_scan3(const int* __restrict__ cnt, const int* __restrict__ bsum,
                                               int* __restrict__ row_ptr, int n) {
    __shared__ int sd[256];
    int t = threadIdx.x;
    int base = blockIdx.x * 1024 + t * 4;
    int v[4];
#pragma unroll
    for (int j = 0; j < 4; j++) { int i = base + j; v[j] = (i < n) ? cnt[i] : 0; }
    int s0 = v[0], s1 = s0 + v[1], s2 = s1 + v[2], s3 = s2 + v[3];
    sd[t] = s3;
    __syncthreads();
    for (int d = 1; d < 256; d <<= 1) {
        int x = (t >= d) ? sd[t - d] : 0;
        __syncthreads();
        sd[t] += x;
        __syncthreads();
    }
    int excl = sd[t] - s3;
    int off = bsum[blockIdx.x] + excl;
    if (base + 0 < n) row_ptr[base + 0] = off;
    if (base + 1 < n) row_ptr[base + 1] = off + s0;
    if (base + 2 < n) row_ptr[base + 2] = off + s1;
    if (base + 3 < n) row_ptr[base + 3] = off + s2;
}

__global__ void k_scatter(const int* __restrict__ src, const int* __restrict__ dst,
                          const float* __restrict__ dinv, int* __restrict__ cursor,
                          int* __restrict__ es_src, float* __restrict__ es_norm, int e) {
    int i = blockIdx.x * blockDim.x + threadIdx.x;
    if (i >= e) return;
    int s = src[i], d = dst[i];
    int pos = atomicAdd(&cursor[d], 1);
    es_src[pos] = s;
    es_norm[pos] = dinv[s] * dinv[d];
}

// ---- W1 transpose+convert: W1[512][128] fp32 -> W1t[128][512] bf16 ------
__global__ __launch_bounds__(256) void k_w1t(const float* __restrict__ W1, ushort_t* __restrict__ W1t) {
    int idx = blockIdx.x * 256 + threadIdx.x;   // 65536
    int nn = idx >> 9, k = idx & 511;
    W1t[idx] = f2bf(W1[(size_t)k * 128 + nn]);
}

// ---- GEMM1 (MFMA bf16): x[n,512] @ W1 -> h bf16 [n,128] -----------------
// Block 256 thr (4 waves), tile M=64 x N=128, BK=64. LDS ~27.6 KB.
// Wave w: rows w*16..+16, all 128 cols (8 col-tiles), acc 8x float4.
__global__ __launch_bounds__(256) void k_gemm1(const float* __restrict__ x,
                                               const ushort_t* __restrict__ W1t,
                                               ushort_t* __restrict__ h, int n) {
    __shared__ ushort_t As[64][72];    // +8 pad: row stride 36 dw -> bank spread
    __shared__ ushort_t Bs[128][72];
    const int tid  = threadIdx.x;
    const int w    = tid >> 6, lane = tid & 63;
    const int quad = lane >> 4, l16 = lane & 15;
    const int row0 = blockIdx.x * 64;

    float4v acc[8];
#pragma unroll
    for (int i = 0; i < 8; i++) acc[i] = (float4v)0.f;

    const int ar  = tid >> 2;           // 0..63
    const int akq = (tid & 3) * 16;     // 0/16/32/48
    const int br  = tid >> 1;           // 0..127
    const int bkq = (tid & 1) * 32;     // 0/32
    const int agrow = row0 + ar;
    const float* xp0 = &x[(size_t)agrow * 512];
    const ushort_t* wp0 = &W1t[(size_t)br * 512];

    for (int kb = 0; kb < 512; kb += 64) {
        // A stage: 64 rows x 64 k, fp32 -> bf16
#pragma unroll
        for (int j = 0; j < 4; j++) {
            float4 v = make_float4(0.f, 0.f, 0.f, 0.f);
            if (agrow < n) v = *(const float4*)(xp0 + kb + akq + j * 4);
            ushort4 b;
            b.x = f2bf(v.x); b.y = f2bf(v.y); b.z = f2bf(v.z); b.w = f2bf(v.w);
            *(ushort4*)&As[ar][akq + j * 4] = b;
        }
        // B stage: 128 n x 64 k bf16 copy
#pragma unroll
        for (int j = 0; j < 8; j++) {
            *(ushort4*)&Bs[br][bkq + j * 4] = *(const ushort4*)(wp0 + kb + bkq + j * 4);
        }
        __syncthreads();
#pragma unroll
        for (int ks = 0; ks < 64; ks += 32) {
            short8 a = *(const short8*)&As[w * 16 + l16][ks + quad * 8];
#pragma unroll
            for (int ct = 0; ct < 8; ct++) {
                short8 b = *(const short8*)&Bs[ct * 16 + l16][ks + quad * 8];
                acc[ct] = __builtin_amdgcn_mfma_f32_16x16x32_bf16(a, b, acc[ct], 0, 0, 0);
            }
        }
        __syncthreads();
    }
    // epilogue: C row = quad*4+reg, col = l16 (within 16x16 tile)
#pragma unroll
    for (int ct = 0; ct < 8; ct++) {
        int col = ct * 16 + l16;
#pragma unroll
        for (int r = 0; r < 4; r++) {
            int grow = row0 + w * 16 + quad * 4 + r;
            if (grow < n) h[(size_t)grow * 128 + col] = f2bf(acc[ct][r]);
        }
    }
}

// ---- agg1: pull-mode over bf16 h, one wave/node, fused bias+relu --------
__global__ __launch_bounds__(256) void k_agg1(const uint* __restrict__ h,
                                              const int* __restrict__ row_ptr,
                                              const int* __restrict__ es_src,
                                              const float* __restrict__ es_norm,
                                              const float* __restrict__ dinv,
                                              const float* __restrict__ b1,
                                              uint* __restrict__ h1, int n) {
    const int tid  = threadIdx.x;
    const int node = blockIdx.x * 4 + (tid >> 6);
    if (node >= n) return;
    const int lane = tid & 63;
    const float di = dinv[node];
    float2 acc = unpack2(h[(size_t)node * 64 + lane]);
    acc.x *= di * di; acc.y *= di * di;
    const int k0 = row_ptr[node], k1 = row_ptr[node + 1];
    int k = k0;
    for (; k + 1 < k1; k += 2) {
        int s0 = es_src[k], s1 = es_src[k + 1];
        float w0 = es_norm[k], w1 = es_norm[k + 1];
        float2 v0 = unpack2(h[(size_t)s0 * 64 + lane]);
        float2 v1 = unpack2(h[(size_t)s1 * 64 + lane]);
        acc.x += v0.x * w0 + v1.x * w1;
        acc.y += v0.y * w0 + v1.y * w1;
    }
    if (k < k1) {
        int s = es_src[k];
        float wgt = es_norm[k];
        float2 v = unpack2(h[(size_t)s * 64 + lane]);
        acc.x += v.x * wgt;
        acc.y += v.y * wgt;
    }
    float2 bb = *(const float2*)&b1[lane * 2];
    acc.x += bb.x; acc.y += bb.y;
    acc.x = acc.x > 0.f ? acc.x : 0.f;
    acc.y = acc.y > 0.f ? acc.y : 0.f;
    h1[(size_t)node * 64 + lane] = pack2(acc.x, acc.y);
}

// ---- GEMM2: bf16 h1[n,128] @ fp32 W2[128,40] -> g fp32 [n,40] -----------
__global__ __launch_bounds__(320) void k_gemm2(const uint* __restrict__ h1,
                                               const float* __restrict__ W2,
                                               float* __restrict__ g, int n) {
    __shared__ float hs[32][132];
    __shared__ float ws[128 * 40];
    const int tid  = threadIdx.x;
    const int row0 = blockIdx.x * 32;
    for (int t = tid; t < 5120; t += 320) ws[t] = W2[t];
    for (int t = tid; t < 1024; t += 320) {   // 32 rows x 32 uint2
        int r = t >> 5;
        int q = t & 31;                        // uint2 index -> cols 4q..4q+3
        int grow = row0 + r;
        float4 v = make_float4(0.f, 0.f, 0.f, 0.f);
        if (grow < n) {
            uint2 u = *(const uint2*)&h1[(size_t)grow * 64 + q * 2];
            float2 a = unpack2(u.x), b = unpack2(u.y);
            v = make_float4(a.x, a.y, b.x, b.y);
        }
        *(float4*)&hs[r][q * 4] = v;
    }
    __syncthreads();
    const int c  = tid % 40;
    const int rg = tid / 40;
    float acc[4] = {0.f, 0.f, 0.f, 0.f};
    for (int k = 0; k < 128; k++) {
        float w = ws[k * 40 + c];
#pragma unroll
        for (int r = 0; r < 4; r++) acc[r] += hs[rg * 4 + r][k] * w;
    }
    for (int r = 0; r < 4; r++) {
        int grow = row0 + rg * 4 + r;
        if (grow < n) g[(size_t)grow * 40 + c] = acc[r];
    }
}

// ---- agg2: pull-mode, D=40, 6 nodes per 256-block, + b2 -----------------
__global__ __launch_bounds__(256) void k_agg2(const float* __restrict__ g,
                                              const int* __restrict__ row_ptr,
                                              const int* __restrict__ es_src,
                                              const float* __restrict__ es_norm,
                                              const float* __restrict__ dinv,
                                              const float* __restrict__ b2,
                                              float* __restrict__ out1, int n) {
    const int tid = threadIdx.x;
    if (tid >= 240) return;
    const int node = blockIdx.x * 6 + tid / 40;
    if (node >= n) return;
    const int c = tid % 40;
    const float di = dinv[node];
    float acc = g[(size_t)node * 40 + c] * di * di;
    const int k0 = row_ptr[node], k1 = row_ptr[node + 1];
    for (int k = k0; k < k1; k++) {
        int s = es_src[k];
        float w = es_norm[k];
        acc += g[(size_t)s * 40 + c] * w;
    }
    out1[(size_t)node * 40 + c] = acc + b2[c];
}

// ---- finalize: out2 = log_softmax(out1) ---------------------------------
__global__ __launch_bounds__(256) void k_finalize(const float* __restrict__ out1,
                                                  float* __restrict__ out2, int n) {
    __shared__ float s[32][41];
    __shared__ float mrow[32], lrow[32];
    const int row0 = blockIdx.x * 32;
    const int tid  = threadIdx.x;
    for (int t = tid; t < 1280; t += 256) {
        int r = t / 40, c = t % 40;
        int grow = row0 + r;
        float v = 0.f;
        if (grow < n) v = out1[(size_t)grow * 40 + c];
        s[r][c] = v;
    }
    __syncthreads();
    if (tid < 32) {
        float m = -1e30f;
        for (int k = 0; k < 40; k++) m = fmaxf(m, s[tid][k]);
        float sum = 0.f;
        for (int k = 0; k < 40; k++) sum += expf(s[tid][k] - m);
        mrow[tid] = m;
        lrow[tid] = logf(sum);
    }
    __syncthreads();
    for (int t = tid; t < 1280; t += 256) {
        int r = t / 40, c = t % 40;
        int grow = row0 + r;
        if (grow < n) out2[(size_t)grow * 40 + c] = s[r][c] - mrow[r] - lrow[r];
    }
}

static inline size_t align4(size_t v) { return (v + 3) & ~(size_t)3; }

extern "C" void kernel_launch(void* const* d_in, const int* in_sizes, int n_in,
                              void* d_out, int out_size, void* d_ws, size_t ws_size,
                              hipStream_t stream) {
    const float* x  = (const float*)d_in[0];
    const int*   ei = (const int*)d_in[1];
    const float* W1 = (const float*)d_in[2];
    const float* b1 = (const float*)d_in[3];
    const float* W2 = (const float*)d_in[4];
    const float* b2 = (const float*)d_in[5];

    const int n = in_sizes[0] / 512;
    const int e = in_sizes[1] / 2;
    const int* src = ei;
    const int* dst = ei + e;

    char* p = (char*)d_ws;
    int*      cnt     = (int*)p;        p += align4(n) * 4;
    int*      row_ptr = (int*)p;        p += align4(n + 1) * 4;
    int*      cursor  = (int*)p;        p += align4(n) * 4;
    float*    dinv    = (float*)p;      p += align4(n) * 4;
    int*      es_src  = (int*)p;        p += align4(e) * 4;
    float*    es_norm = (float*)p;      p += align4(e) * 4;
    ushort_t* W1t     = (ushort_t*)p;   p += (size_t)128 * 512 * 2;
    ushort_t* h       = (ushort_t*)p;   p += (size_t)n * 128 * 2;   // bf16; g overlays later
    ushort_t* h1      = (ushort_t*)p;   p += (size_t)n * 128 * 2;   // bf16
    float*    g       = (float*)h;      // h dead after agg1; g = n*40 fp32 fits n*128*2
    float*    out1    = (float*)d_out;
    float*    out2    = out1 + (size_t)n * 40;

    const int B = 256;
    const int nb = (n + 1023) / 1024;

    // CSR build
    hipMemsetAsync(cnt, 0, (size_t)n * 4, stream);
    k_hist<<<(e + B - 1) / B, B, 0, stream>>>(dst, cnt, e);
    k_dinv<<<(n + B - 1) / B, B, 0, stream>>>(cnt, dinv, n);
    k_scan1<<<nb, 256, 0, stream>>>(cnt, cursor, n);
    k_scan2<<<1, 64, 0, stream>>>(cursor, nb, row_ptr, n, e);
    k_scan3<<<nb, 256, 0, stream>>>(cnt, cursor, row_ptr, n);
    hipMemcpyAsync(cursor, row_ptr, (size_t)n * 4, hipMemcpyDeviceToDevice, stream);
    k_scatter<<<(e + B - 1) / B, B, 0, stream>>>(src, dst, dinv, cursor, es_src, es_norm, e);

    // weights prep + layer 1
    k_w1t<<<256, 256, 0, stream>>>(W1, W1t);
    k_gemm1<<<(n + 63) / 64, 256, 0, stream>>>(x, W1t, h, n);
    k_agg1<<<(n + 3) / 4, 256, 0, stream>>>((const uint*)h, row_ptr, es_src, es_norm, dinv, b1, (uint*)h1, n);

    // layer 2
    k_gemm2<<<(n + 31) / 32, 320, 0, stream>>>((const uint*)h1, W2, g, n);
    k_agg2<<<(n + 5) / 6, 256, 0, stream>>>(g, row_ptr, es_src, es_norm, dinv, b2, out1, n);

    k_finalize<<<(n + 31) / 32, 256, 0, stream>>>(out1, out2, n);
}

// Round 4
// 784.820 us; speedup vs baseline: 5.4267x; 1.0013x over previous
//
#include <hip/hip_runtime.h>
#include <math.h>

// GCN 2-layer forward on MI355X — round 4.
//  - es_norm eliminated: h' = dinv*h folded into GEMM epilogues,
//    agg does pure gather-sum then one dinv scale.  Scatter writes 4B/edge.
//  - GEMM2 now MFMA bf16 (W2^T zero-padded to 48 cols).
//  - log_softmax fused into agg2.

typedef unsigned int uint;
typedef unsigned short ushort_t;
using short8  = __attribute__((ext_vector_type(8))) short;
using float4v = __attribute__((ext_vector_type(4))) float;

__device__ __forceinline__ ushort_t f2bf(float f) {
    uint u = __float_as_uint(f);
    u += 0x7FFFu + ((u >> 16) & 1u);   // RNE
    return (ushort_t)(u >> 16);
}
__device__ __forceinline__ float2 unpack2(uint v) {
    return make_float2(__uint_as_float(v << 16), __uint_as_float(v & 0xFFFF0000u));
}
__device__ __forceinline__ uint pack2(float a, float b) {
    return (uint)f2bf(a) | ((uint)f2bf(b) << 16);
}

// ---------------- CSR build ----------------------------------------------

__global__ void k_hist(const int* __restrict__ dst, int* __restrict__ cnt, int e) {
    int i = blockIdx.x * blockDim.x + threadIdx.x;
    if (i < e) atomicAdd(&cnt[dst[i]], 1);
}

__global__ void k_dinv(const int* __restrict__ cnt, float* __restrict__ dinv, int n) {
    int i = blockIdx.x * blockDim.x + threadIdx.x;
    if (i < n) dinv[i] = rsqrtf((float)(cnt[i] + 1));
}

__global__ __launch_bounds__(256) void k_scan1(const int* __restrict__ cnt, int* __restrict__ bsum, int n) {
    __shared__ int sd[256];
    int t = threadIdx.x;
    int base = blockIdx.x * 1024 + t * 4;
    int s = 0;
#pragma unroll
    for (int j = 0; j < 4; j++) { int i = base + j; if (i < n) s += cnt[i]; }
    sd[t] = s;
    __syncthreads();
    for (int d = 128; d > 0; d >>= 1) {
        if (t < d) sd[t] += sd[t + d];
        __syncthreads();
    }
    if (t == 0) bsum[blockIdx.x] = sd[0];
}

__global__ void k_scan2(int* __restrict__ bsum, int nb, int* __restrict__ row_ptr, int n, int e) {
    if (threadIdx.x == 0 && blockIdx.x == 0) {
        int run = 0;
        for (int i = 0; i < nb; i++) { int v = bsum[i]; bsum[i] = run; run += v; }
        row_ptr[n] = e;
    }
}

__global__ __launch_bounds__(256) void k_scan3(const int* __restrict__ cnt, const int* __restrict__ bsum,
                                               int* __restrict__ row_ptr, int n) {
    __shared__ int sd[256];
    int t = threadIdx.x;
    int base = blockIdx.x * 1024 + t * 4;
    int v[4];
#pragma unroll
    for (int j = 0; j < 4; j++) { int i = base + j; v[j] = (i < n) ? cnt[i] : 0; }
    int s0 = v[0], s1 = s0 + v[1], s2 = s1 + v[2], s3 = s2 + v[3];
    sd[t] = s3;
    __syncthreads();
    for (int d = 1; d < 256; d <<= 1) {
        int x = (t >= d) ? sd[t - d] : 0;
        __syncthreads();
        sd[t] += x;
        __syncthreads();
    }
    int excl = sd[t] - s3;
    int off = bsum[blockIdx.x] + excl;
    if (base + 0 < n) row_ptr[base + 0] = off;
    if (base + 1 < n) row_ptr[base + 1] = off + s0;
    if (base + 2 < n) row_ptr[base + 2] = off + s1;
    if (base + 3 < n) row_ptr[base + 3] = off + s2;
}

// single 4B scattered write per edge
__global__ void k_scatter(const int* __restrict__ src, const int* __restrict__ dst,
                          int* __restrict__ cursor, int* __restrict__ es_src, int e) {
    int i = blockIdx.x * blockDim.x + threadIdx.x;
    if (i >= e) return;
    int s = src[i], d = dst[i];
    int pos = atomicAdd(&cursor[d], 1);
    es_src[pos] = s;
}

// ---- weight prep --------------------------------------------------------
__global__ __launch_bounds__(256) void k_w1t(const float* __restrict__ W1, ushort_t* __restrict__ W1t) {
    int idx = blockIdx.x * 256 + threadIdx.x;   // 65536
    int nn = idx >> 9, k = idx & 511;
    W1t[idx] = f2bf(W1[(size_t)k * 128 + nn]);
}

// W2[128][40] fp32 -> W2t[48][128] bf16 (cols 40..47 zero)
__global__ __launch_bounds__(256) void k_w2t(const float* __restrict__ W2, ushort_t* __restrict__ W2t) {
    int idx = blockIdx.x * 256 + threadIdx.x;   // 6144
    if (idx >= 6144) return;
    int c = idx >> 7, k = idx & 127;
    W2t[idx] = (c < 40) ? f2bf(W2[(size_t)k * 40 + c]) : (ushort_t)0;
}

// ---- GEMM1 (MFMA bf16): h'[i] = bf16(dinv[i] * (x @ W1)[i]) -------------
__global__ __launch_bounds__(256) void k_gemm1(const float* __restrict__ x,
                                               const ushort_t* __restrict__ W1t,
                                               const float* __restrict__ dinv,
                                               ushort_t* __restrict__ h, int n) {
    __shared__ ushort_t As[64][72];
    __shared__ ushort_t Bs[128][72];
    const int tid  = threadIdx.x;
    const int w    = tid >> 6, lane = tid & 63;
    const int quad = lane >> 4, l16 = lane & 15;
    const int row0 = blockIdx.x * 64;

    float4v acc[8];
#pragma unroll
    for (int i = 0; i < 8; i++) acc[i] = (float4v)0.f;

    const int ar  = tid >> 2;
    const int akq = (tid & 3) * 16;
    const int br  = tid >> 1;
    const int bkq = (tid & 1) * 32;
    const int agrow = row0 + ar;
    const float* xp0 = &x[(size_t)agrow * 512];
    const ushort_t* wp0 = &W1t[(size_t)br * 512];

    for (int kb = 0; kb < 512; kb += 64) {
#pragma unroll
        for (int j = 0; j < 4; j++) {
            float4 v = make_float4(0.f, 0.f, 0.f, 0.f);
            if (agrow < n) v = *(const float4*)(xp0 + kb + akq + j * 4);
            ushort4 b;
            b.x = f2bf(v.x); b.y = f2bf(v.y); b.z = f2bf(v.z); b.w = f2bf(v.w);
            *(ushort4*)&As[ar][akq + j * 4] = b;
        }
#pragma unroll
        for (int j = 0; j < 8; j++) {
            *(ushort4*)&Bs[br][bkq + j * 4] = *(const ushort4*)(wp0 + kb + bkq + j * 4);
        }
        __syncthreads();
#pragma unroll
        for (int ks = 0; ks < 64; ks += 32) {
            short8 a = *(const short8*)&As[w * 16 + l16][ks + quad * 8];
#pragma unroll
            for (int ct = 0; ct < 8; ct++) {
                short8 b = *(const short8*)&Bs[ct * 16 + l16][ks + quad * 8];
                acc[ct] = __builtin_amdgcn_mfma_f32_16x16x32_bf16(a, b, acc[ct], 0, 0, 0);
            }
        }
        __syncthreads();
    }
#pragma unroll
    for (int r = 0; r < 4; r++) {
        int grow = row0 + w * 16 + quad * 4 + r;
        if (grow >= n) continue;
        float di = dinv[grow];
#pragma unroll
        for (int ct = 0; ct < 8; ct++) {
            int col = ct * 16 + l16;
            h[(size_t)grow * 128 + col] = f2bf(di * acc[ct][r]);
        }
    }
}

// ---- agg1: h1 = bf16(relu(dinv[node]*(h'[node]+Σ h'[src]) + b1)) --------
__global__ __launch_bounds__(256) void k_agg1(const uint* __restrict__ h,
                                              const int* __restrict__ row_ptr,
                                              const int* __restrict__ es_src,
                                              const float* __restrict__ dinv,
                                              const float* __restrict__ b1,
                                              uint* __restrict__ h1, int n) {
    const int tid  = threadIdx.x;
    const int node = blockIdx.x * 4 + (tid >> 6);
    if (node >= n) return;
    const int lane = tid & 63;
    float2 acc = unpack2(h[(size_t)node * 64 + lane]);   // self term (h')
    const int k0 = row_ptr[node], k1 = row_ptr[node + 1];
    int k = k0;
    for (; k + 1 < k1; k += 2) {
        int s0 = es_src[k], s1 = es_src[k + 1];
        float2 v0 = unpack2(h[(size_t)s0 * 64 + lane]);
        float2 v1 = unpack2(h[(size_t)s1 * 64 + lane]);
        acc.x += v0.x + v1.x;
        acc.y += v0.y + v1.y;
    }
    if (k < k1) {
        int s = es_src[k];
        float2 v = unpack2(h[(size_t)s * 64 + lane]);
        acc.x += v.x;
        acc.y += v.y;
    }
    const float di = dinv[node];
    float2 bb = *(const float2*)&b1[lane * 2];
    acc.x = di * acc.x + bb.x;
    acc.y = di * acc.y + bb.y;
    acc.x = acc.x > 0.f ? acc.x : 0.f;
    acc.y = acc.y > 0.f ? acc.y : 0.f;
    h1[(size_t)node * 64 + lane] = pack2(acc.x, acc.y);
}

// ---- GEMM2 (MFMA bf16): g'[i] = dinv[i] * (h1 @ W2)[i], fp32 [n,40] -----
__global__ __launch_bounds__(256) void k_gemm2(const ushort_t* __restrict__ h1,
                                               const ushort_t* __restrict__ W2t,
                                               const float* __restrict__ dinv,
                                               float* __restrict__ g, int n) {
    __shared__ ushort_t As[64][136];   // 64 rows x 128 k (+8 pad)
    __shared__ ushort_t Bs[48][136];   // 48 cols x 128 k
    const int tid  = threadIdx.x;
    const int w    = tid >> 6, lane = tid & 63;
    const int quad = lane >> 4, l16 = lane & 15;
    const int row0 = blockIdx.x * 64;

    // stage A: 64 x 128 bf16, 4x uint4 per thread
    {
        int ar = tid >> 2;
        int ak = (tid & 3) * 32;
        int grow = row0 + ar;
#pragma unroll
        for (int j = 0; j < 4; j++) {
            uint4 v = make_uint4(0, 0, 0, 0);
            if (grow < n) v = *(const uint4*)&h1[(size_t)grow * 128 + ak + j * 8];
            *(uint4*)&As[ar][ak + j * 8] = v;
        }
    }
    // stage B: 48 x 128 bf16 = 768 uint4
    for (int i = tid; i < 768; i += 256) {
        int row = i >> 4, q = i & 15;
        *(uint4*)&Bs[row][q * 8] = *(const uint4*)&W2t[(size_t)row * 128 + q * 8];
    }
    __syncthreads();

    float4v acc[3];
#pragma unroll
    for (int i = 0; i < 3; i++) acc[i] = (float4v)0.f;
#pragma unroll
    for (int ks = 0; ks < 128; ks += 32) {
        short8 a = *(const short8*)&As[w * 16 + l16][ks + quad * 8];
#pragma unroll
        for (int ct = 0; ct < 3; ct++) {
            short8 b = *(const short8*)&Bs[ct * 16 + l16][ks + quad * 8];
            acc[ct] = __builtin_amdgcn_mfma_f32_16x16x32_bf16(a, b, acc[ct], 0, 0, 0);
        }
    }
#pragma unroll
    for (int r = 0; r < 4; r++) {
        int grow = row0 + w * 16 + quad * 4 + r;
        if (grow >= n) continue;
        float di = dinv[grow];
#pragma unroll
        for (int ct = 0; ct < 3; ct++) {
            int col = ct * 16 + l16;
            if (col < 40) g[(size_t)grow * 40 + col] = di * acc[ct][r];
        }
    }
}

// ---- agg2 + bias + log_softmax fused ------------------------------------
// 256 thr: 6 nodes x 40 cols (threads 240..255 idle in compute).
__global__ __launch_bounds__(256) void k_agg2f(const float* __restrict__ g,
                                               const int* __restrict__ row_ptr,
                                               const int* __restrict__ es_src,
                                               const float* __restrict__ dinv,
                                               const float* __restrict__ b2,
                                               float* __restrict__ out1,
                                               float* __restrict__ out2, int n) {
    __shared__ float s[6][40];
    __shared__ float mrow[6], lrow[6];
    const int tid = threadIdx.x;
    const int nl  = tid / 40;            // node-local 0..6
    const int c   = tid % 40;
    const int node = blockIdx.x * 6 + nl;
    const bool active = (tid < 240) && (node < n);

    float v = 0.f;
    if (active) {
        float acc = g[(size_t)node * 40 + c];   // self term (g')
        const int k0 = row_ptr[node], k1 = row_ptr[node + 1];
        for (int k = k0; k < k1; k++) {
            int src = es_src[k];
            acc += g[(size_t)src * 40 + c];
        }
        v = dinv[node] * acc + b2[c];
        s[nl][c] = v;
        out1[(size_t)node * 40 + c] = v;
    }
    __syncthreads();
    if (tid < 6 && blockIdx.x * 6 + tid < n) {
        float m = -1e30f;
        for (int k = 0; k < 40; k++) m = fmaxf(m, s[tid][k]);
        float sum = 0.f;
        for (int k = 0; k < 40; k++) sum += expf(s[tid][k] - m);
        mrow[tid] = m;
        lrow[tid] = logf(sum);
    }
    __syncthreads();
    if (active) out2[(size_t)node * 40 + c] = v - mrow[nl] - lrow[nl];
}

static inline size_t align4(size_t v) { return (v + 3) & ~(size_t)3; }

extern "C" void kernel_launch(void* const* d_in, const int* in_sizes, int n_in,
                              void* d_out, int out_size, void* d_ws, size_t ws_size,
                              hipStream_t stream) {
    const float* x  = (const float*)d_in[0];
    const int*   ei = (const int*)d_in[1];
    const float* W1 = (const float*)d_in[2];
    const float* b1 = (const float*)d_in[3];
    const float* W2 = (const float*)d_in[4];
    const float* b2 = (const float*)d_in[5];

    const int n = in_sizes[0] / 512;
    const int e = in_sizes[1] / 2;
    const int* src = ei;
    const int* dst = ei + e;

    char* p = (char*)d_ws;
    int*      cnt     = (int*)p;        p += align4(n) * 4;
    int*      row_ptr = (int*)p;        p += align4(n + 1) * 4;
    int*      cursor  = (int*)p;        p += align4(n) * 4;
    float*    dinv    = (float*)p;      p += align4(n) * 4;
    int*      es_src  = (int*)p;        p += align4(e) * 4;
    ushort_t* W1t     = (ushort_t*)p;   p += (size_t)128 * 512 * 2;
    ushort_t* W2t     = (ushort_t*)p;   p += (size_t)48 * 128 * 2;
    ushort_t* h       = (ushort_t*)p;   p += (size_t)n * 128 * 2;   // h' bf16; g overlays
    ushort_t* h1      = (ushort_t*)p;   p += (size_t)n * 128 * 2;   // bf16
    float*    g       = (float*)h;      // h dead after agg1; n*40 fp32 fits
    float*    out1    = (float*)d_out;
    float*    out2    = out1 + (size_t)n * 40;

    const int B = 256;
    const int nb = (n + 1023) / 1024;

    // CSR build
    hipMemsetAsync(cnt, 0, (size_t)n * 4, stream);
    k_hist<<<(e + B - 1) / B, B, 0, stream>>>(dst, cnt, e);
    k_dinv<<<(n + B - 1) / B, B, 0, stream>>>(cnt, dinv, n);
    k_scan1<<<nb, 256, 0, stream>>>(cnt, cursor, n);
    k_scan2<<<1, 64, 0, stream>>>(cursor, nb, row_ptr, n, e);
    k_scan3<<<nb, 256, 0, stream>>>(cnt, cursor, row_ptr, n);
    hipMemcpyAsync(cursor, row_ptr, (size_t)n * 4, hipMemcpyDeviceToDevice, stream);
    k_scatter<<<(e + B - 1) / B, B, 0, stream>>>(src, dst, cursor, es_src, e);

    // weights
    k_w1t<<<256, 256, 0, stream>>>(W1, W1t);
    k_w2t<<<24, 256, 0, stream>>>(W2, W2t);

    // layer 1
    k_gemm1<<<(n + 63) / 64, 256, 0, stream>>>(x, W1t, dinv, h, n);
    k_agg1<<<(n + 3) / 4, 256, 0, stream>>>((const uint*)h, row_ptr, es_src, dinv, b1, (uint*)h1, n);

    // layer 2
    k_gemm2<<<(n + 63) / 64, 256, 0, stream>>>(h1, W2t, dinv, g, n);
    k_agg2f<<<(n + 5) / 6, 256, 0, stream>>>(g, row_ptr, es_src, dinv, b2, out1, out2, n);
}

// Round 5
// 572.917 us; speedup vs baseline: 7.4339x; 1.3699x over previous
//
#include <hip/hip_runtime.h>
#include <math.h>

// GCN 2-layer forward on MI355X — round 5.
//  CSR build rewritten as 2-level counting sort (bucket = dst>>7):
//    k_bhist -> k_bscan -> k_part (packed (dstlocal<<25)|src) -> k_bsort
//  k_bsort also emits cnt + row_ptr (kills k_hist, 3 scans, memcpy, scatter).
//  Aggs: pull-mode with unroll-4 gather.

typedef unsigned int uint;
typedef unsigned short ushort_t;
using short8  = __attribute__((ext_vector_type(8))) short;
using float4v = __attribute__((ext_vector_type(4))) float;

__device__ __forceinline__ ushort_t f2bf(float f) {
    uint u = __float_as_uint(f);
    u += 0x7FFFu + ((u >> 16) & 1u);   // RNE
    return (ushort_t)(u >> 16);
}
__device__ __forceinline__ float2 unpack2(uint v) {
    return make_float2(__uint_as_float(v << 16), __uint_as_float(v & 0xFFFF0000u));
}
__device__ __forceinline__ uint pack2(float a, float b) {
    return (uint)f2bf(a) | ((uint)f2bf(b) << 16);
}

// ---------------- bucket counting sort -----------------------------------
// NB = ceil(n/128) buckets (<= 800 for n <= 102400).

__global__ __launch_bounds__(256) void k_bhist(const int* __restrict__ dst,
                                               int* __restrict__ bcnt, int e, int nb) {
    __shared__ int h[800];
    for (int t = threadIdx.x; t < nb; t += 256) h[t] = 0;
    __syncthreads();
    int ibase = blockIdx.x * 2560 + threadIdx.x;
#pragma unroll
    for (int j = 0; j < 10; j++) {
        int i = ibase + j * 256;
        if (i < e) atomicAdd(&h[dst[i] >> 7], 1);
    }
    __syncthreads();
    for (int t = threadIdx.x; t < nb; t += 256) {
        int c = h[t];
        if (c) atomicAdd(&bcnt[t], c);
    }
}

// one block: exclusive scan of nb (<1024) bucket counts
__global__ __launch_bounds__(256) void k_bscan(const int* __restrict__ bcnt, int* __restrict__ bbase,
                                               int* __restrict__ bcur, int* __restrict__ row_ptr,
                                               int nb, int n, int e) {
    __shared__ int sd[256];
    int t = threadIdx.x;
    int base = t * 4;
    int v[4];
#pragma unroll
    for (int j = 0; j < 4; j++) v[j] = (base + j < nb) ? bcnt[base + j] : 0;
    int s0 = v[0], s1 = s0 + v[1], s2 = s1 + v[2], s3 = s2 + v[3];
    sd[t] = s3;
    __syncthreads();
    for (int d = 1; d < 256; d <<= 1) {
        int x = (t >= d) ? sd[t - d] : 0;
        __syncthreads();
        sd[t] += x;
        __syncthreads();
    }
    int excl = sd[t] - s3;
    int pre0 = excl, pre1 = excl + s0, pre2 = excl + s1, pre3 = excl + s2;
    if (base + 0 < nb) { bbase[base + 0] = pre0; bcur[base + 0] = pre0; }
    if (base + 1 < nb) { bbase[base + 1] = pre1; bcur[base + 1] = pre1; }
    if (base + 2 < nb) { bbase[base + 2] = pre2; bcur[base + 2] = pre2; }
    if (base + 3 < nb) { bbase[base + 3] = pre3; bcur[base + 3] = pre3; }
    if (t == 255) bbase[nb] = excl + s3;   // == e
    if (t == 0) row_ptr[n] = e;
}

// partition: packed (dstlocal<<25)|src into bucket regions
__global__ __launch_bounds__(256) void k_part(const int* __restrict__ src, const int* __restrict__ dst,
                                              int* __restrict__ bcur, uint* __restrict__ pbuf,
                                              int e, int nb) {
    __shared__ int h[800];
    __shared__ int base_l[800];
    for (int t = threadIdx.x; t < nb; t += 256) h[t] = 0;
    __syncthreads();
    uint pk[10]; int bk[10]; int lp[10];
    int ibase = blockIdx.x * 2560 + threadIdx.x;
#pragma unroll
    for (int j = 0; j < 10; j++) {
        int i = ibase + j * 256;
        bk[j] = -1;
        if (i < e) {
            int s = src[i], d = dst[i];
            int b = d >> 7;
            bk[j] = b;
            pk[j] = ((uint)(d & 127) << 25) | (uint)s;
            lp[j] = atomicAdd(&h[b], 1);
        }
    }
    __syncthreads();
    for (int t = threadIdx.x; t < nb; t += 256) {
        int c = h[t];
        base_l[t] = c ? atomicAdd(&bcur[t], c) : 0;
    }
    __syncthreads();
#pragma unroll
    for (int j = 0; j < 10; j++) {
        if (bk[j] >= 0) pbuf[base_l[bk[j]] + lp[j]] = pk[j];
    }
}

// per-bucket fine sort: emits cnt, row_ptr, es_src
__global__ __launch_bounds__(256) void k_bsort(const uint* __restrict__ pbuf,
                                               const int* __restrict__ bbase,
                                               int* __restrict__ cnt,
                                               int* __restrict__ row_ptr,
                                               int* __restrict__ es_src, int n) {
    __shared__ int cl[128];
    __shared__ int cur[128];
    const int b = blockIdx.x;
    const int tid = threadIdx.x;
    const int ebeg = bbase[b], eend = bbase[b + 1];
    const int m = eend - ebeg;
    if (tid < 128) cl[tid] = 0;
    __syncthreads();
    for (int i = tid; i < m; i += 256) {
        uint p = pbuf[ebeg + i];
        atomicAdd(&cl[p >> 25], 1);
    }
    __syncthreads();
    int own = (tid < 128) ? cl[tid] : 0;
    for (int d = 1; d < 128; d <<= 1) {
        int v = 0;
        if (tid < 128 && tid >= d) v = cl[tid - d];
        __syncthreads();
        if (tid < 128 && tid >= d) cl[tid] += v;
        __syncthreads();
    }
    if (tid < 128) {
        int excl = cl[tid] - own;
        int node = b * 128 + tid;
        if (node < n) {
            cnt[node] = own;
            row_ptr[node] = ebeg + excl;
        }
        cur[tid] = excl;
    }
    __syncthreads();
    for (int i = tid; i < m; i += 256) {
        uint p = pbuf[ebeg + i];
        int dl = (int)(p >> 25);
        int pos = atomicAdd(&cur[dl], 1);
        es_src[ebeg + pos] = (int)(p & 0x1FFFFFFu);
    }
}

__global__ void k_dinv(const int* __restrict__ cnt, float* __restrict__ dinv, int n) {
    int i = blockIdx.x * blockDim.x + threadIdx.x;
    if (i < n) dinv[i] = rsqrtf((float)(cnt[i] + 1));
}

// ---- weight prep --------------------------------------------------------
__global__ __launch_bounds__(256) void k_w1t(const float* __restrict__ W1, ushort_t* __restrict__ W1t) {
    int idx = blockIdx.x * 256 + threadIdx.x;   // 65536
    int nn = idx >> 9, k = idx & 511;
    W1t[idx] = f2bf(W1[(size_t)k * 128 + nn]);
}

__global__ __launch_bounds__(256) void k_w2t(const float* __restrict__ W2, ushort_t* __restrict__ W2t) {
    int idx = blockIdx.x * 256 + threadIdx.x;   // 6144
    if (idx >= 6144) return;
    int c = idx >> 7, k = idx & 127;
    W2t[idx] = (c < 40) ? f2bf(W2[(size_t)k * 40 + c]) : (ushort_t)0;
}

// ---- GEMM1 (MFMA bf16): h'[i] = bf16(dinv[i] * (x @ W1)[i]) -------------
__global__ __launch_bounds__(256) void k_gemm1(const float* __restrict__ x,
                                               const ushort_t* __restrict__ W1t,
                                               const float* __restrict__ dinv,
                                               ushort_t* __restrict__ h, int n) {
    __shared__ ushort_t As[64][72];
    __shared__ ushort_t Bs[128][72];
    const int tid  = threadIdx.x;
    const int w    = tid >> 6, lane = tid & 63;
    const int quad = lane >> 4, l16 = lane & 15;
    const int row0 = blockIdx.x * 64;

    float4v acc[8];
#pragma unroll
    for (int i = 0; i < 8; i++) acc[i] = (float4v)0.f;

    const int ar  = tid >> 2;
    const int akq = (tid & 3) * 16;
    const int br  = tid >> 1;
    const int bkq = (tid & 1) * 32;
    const int agrow = row0 + ar;
    const float* xp0 = &x[(size_t)agrow * 512];
    const ushort_t* wp0 = &W1t[(size_t)br * 512];

    for (int kb = 0; kb < 512; kb += 64) {
#pragma unroll
        for (int j = 0; j < 4; j++) {
            float4 v = make_float4(0.f, 0.f, 0.f, 0.f);
            if (agrow < n) v = *(const float4*)(xp0 + kb + akq + j * 4);
            ushort4 b;
            b.x = f2bf(v.x); b.y = f2bf(v.y); b.z = f2bf(v.z); b.w = f2bf(v.w);
            *(ushort4*)&As[ar][akq + j * 4] = b;
        }
#pragma unroll
        for (int j = 0; j < 8; j++) {
            *(ushort4*)&Bs[br][bkq + j * 4] = *(const ushort4*)(wp0 + kb + bkq + j * 4);
        }
        __syncthreads();
#pragma unroll
        for (int ks = 0; ks < 64; ks += 32) {
            short8 a = *(const short8*)&As[w * 16 + l16][ks + quad * 8];
#pragma unroll
            for (int ct = 0; ct < 8; ct++) {
                short8 b = *(const short8*)&Bs[ct * 16 + l16][ks + quad * 8];
                acc[ct] = __builtin_amdgcn_mfma_f32_16x16x32_bf16(a, b, acc[ct], 0, 0, 0);
            }
        }
        __syncthreads();
    }
#pragma unroll
    for (int r = 0; r < 4; r++) {
        int grow = row0 + w * 16 + quad * 4 + r;
        if (grow >= n) continue;
        float di = dinv[grow];
#pragma unroll
        for (int ct = 0; ct < 8; ct++) {
            int col = ct * 16 + l16;
            h[(size_t)grow * 128 + col] = f2bf(di * acc[ct][r]);
        }
    }
}

// ---- agg1: h1 = bf16(relu(dinv[node]*(h'[node]+Σ h'[src]) + b1)) --------
__global__ __launch_bounds__(256) void k_agg1(const uint* __restrict__ h,
                                              const int* __restrict__ row_ptr,
                                              const int* __restrict__ es_src,
                                              const float* __restrict__ dinv,
                                              const float* __restrict__ b1,
                                              uint* __restrict__ h1, int n) {
    const int tid  = threadIdx.x;
    const int node = blockIdx.x * 4 + (tid >> 6);
    if (node >= n) return;
    const int lane = tid & 63;
    float2 acc = unpack2(h[(size_t)node * 64 + lane]);   // self term
    const int k0 = row_ptr[node], k1 = row_ptr[node + 1];
    int k = k0;
    for (; k + 3 < k1; k += 4) {
        int s0 = es_src[k], s1 = es_src[k + 1], s2 = es_src[k + 2], s3 = es_src[k + 3];
        float2 v0 = unpack2(h[(size_t)s0 * 64 + lane]);
        float2 v1 = unpack2(h[(size_t)s1 * 64 + lane]);
        float2 v2 = unpack2(h[(size_t)s2 * 64 + lane]);
        float2 v3 = unpack2(h[(size_t)s3 * 64 + lane]);
        acc.x += (v0.x + v1.x) + (v2.x + v3.x);
        acc.y += (v0.y + v1.y) + (v2.y + v3.y);
    }
    for (; k < k1; k++) {
        int s = es_src[k];
        float2 v = unpack2(h[(size_t)s * 64 + lane]);
        acc.x += v.x;
        acc.y += v.y;
    }
    const float di = dinv[node];
    float2 bb = *(const float2*)&b1[lane * 2];
    acc.x = di * acc.x + bb.x;
    acc.y = di * acc.y + bb.y;
    acc.x = acc.x > 0.f ? acc.x : 0.f;
    acc.y = acc.y > 0.f ? acc.y : 0.f;
    h1[(size_t)node * 64 + lane] = pack2(acc.x, acc.y);
}

// ---- GEMM2 (MFMA bf16): g'[i] = dinv[i] * (h1 @ W2)[i], fp32 [n,40] -----
__global__ __launch_bounds__(256) void k_gemm2(const ushort_t* __restrict__ h1,
                                               const ushort_t* __restrict__ W2t,
                                               const float* __restrict__ dinv,
                                               float* __restrict__ g, int n) {
    __shared__ ushort_t As[64][136];
    __shared__ ushort_t Bs[48][136];
    const int tid  = threadIdx.x;
    const int w    = tid >> 6, lane = tid & 63;
    const int quad = lane >> 4, l16 = lane & 15;
    const int row0 = blockIdx.x * 64;

    {
        int ar = tid >> 2;
        int ak = (tid & 3) * 32;
        int grow = row0 + ar;
#pragma unroll
        for (int j = 0; j < 4; j++) {
            uint4 v = make_uint4(0, 0, 0, 0);
            if (grow < n) v = *(const uint4*)&h1[(size_t)grow * 128 + ak + j * 8];
            *(uint4*)&As[ar][ak + j * 8] = v;
        }
    }
    for (int i = tid; i < 768; i += 256) {
        int row = i >> 4, q = i & 15;
        *(uint4*)&Bs[row][q * 8] = *(const uint4*)&W2t[(size_t)row * 128 + q * 8];
    }
    __syncthreads();

    float4v acc[3];
#pragma unroll
    for (int i = 0; i < 3; i++) acc[i] = (float4v)0.f;
#pragma unroll
    for (int ks = 0; ks < 128; ks += 32) {
        short8 a = *(const short8*)&As[w * 16 + l16][ks + quad * 8];
#pragma unroll
        for (int ct = 0; ct < 3; ct++) {
            short8 b = *(const short8*)&Bs[ct * 16 + l16][ks + quad * 8];
            acc[ct] = __builtin_amdgcn_mfma_f32_16x16x32_bf16(a, b, acc[ct], 0, 0, 0);
        }
    }
#pragma unroll
    for (int r = 0; r < 4; r++) {
        int grow = row0 + w * 16 + quad * 4 + r;
        if (grow >= n) continue;
        float di = dinv[grow];
#pragma unroll
        for (int ct = 0; ct < 3; ct++) {
            int col = ct * 16 + l16;
            if (col < 40) g[(size_t)grow * 40 + col] = di * acc[ct][r];
        }
    }
}

// ---- agg2 + bias + log_softmax fused ------------------------------------
__global__ __launch_bounds__(256) void k_agg2f(const float* __restrict__ g,
                                               const int* __restrict__ row_ptr,
                                               const int* __restrict__ es_src,
                                               const float* __restrict__ dinv,
                                               const float* __restrict__ b2,
                                               float* __restrict__ out1,
                                               float* __restrict__ out2, int n) {
    __shared__ float s[6][40];
    __shared__ float mrow[6], lrow[6];
    const int tid = threadIdx.x;
    const int nl  = tid / 40;
    const int c   = tid % 40;
    const int node = blockIdx.x * 6 + nl;
    const bool active = (tid < 240) && (node < n);

    float v = 0.f;
    if (active) {
        float acc = g[(size_t)node * 40 + c];   // self term
        const int k0 = row_ptr[node], k1 = row_ptr[node + 1];
        int k = k0;
        for (; k + 3 < k1; k += 4) {
            int s0 = es_src[k], s1 = es_src[k + 1], s2 = es_src[k + 2], s3 = es_src[k + 3];
            float a0 = g[(size_t)s0 * 40 + c];
            float a1 = g[(size_t)s1 * 40 + c];
            float a2 = g[(size_t)s2 * 40 + c];
            float a3 = g[(size_t)s3 * 40 + c];
            acc += (a0 + a1) + (a2 + a3);
        }
        for (; k < k1; k++) acc += g[(size_t)es_src[k] * 40 + c];
        v = dinv[node] * acc + b2[c];
        s[nl][c] = v;
        out1[(size_t)node * 40 + c] = v;
    }
    __syncthreads();
    if (tid < 6 && blockIdx.x * 6 + tid < n) {
        float m = -1e30f;
        for (int k = 0; k < 40; k++) m = fmaxf(m, s[tid][k]);
        float sum = 0.f;
        for (int k = 0; k < 40; k++) sum += expf(s[tid][k] - m);
        mrow[tid] = m;
        lrow[tid] = logf(sum);
    }
    __syncthreads();
    if (active) out2[(size_t)node * 40 + c] = v - mrow[nl] - lrow[nl];
}

static inline size_t align4(size_t v) { return (v + 3) & ~(size_t)3; }

extern "C" void kernel_launch(void* const* d_in, const int* in_sizes, int n_in,
                              void* d_out, int out_size, void* d_ws, size_t ws_size,
                              hipStream_t stream) {
    const float* x  = (const float*)d_in[0];
    const int*   ei = (const int*)d_in[1];
    const float* W1 = (const float*)d_in[2];
    const float* b1 = (const float*)d_in[3];
    const float* W2 = (const float*)d_in[4];
    const float* b2 = (const float*)d_in[5];

    const int n = in_sizes[0] / 512;
    const int e = in_sizes[1] / 2;
    const int* src = ei;
    const int* dst = ei + e;
    const int NB = (n + 127) >> 7;           // buckets of 128 nodes (<=800)

    char* p = (char*)d_ws;
    int*      bcnt    = (int*)p;        p += align4(NB) * 4;
    int*      bbase   = (int*)p;        p += align4(NB + 1) * 4;
    int*      bcur    = (int*)p;        p += align4(NB) * 4;
    int*      cnt     = (int*)p;        p += align4(n) * 4;
    int*      row_ptr = (int*)p;        p += align4(n + 1) * 4;
    float*    dinv    = (float*)p;      p += align4(n) * 4;
    uint*     pbuf    = (uint*)p;       p += align4(e) * 4;
    int*      es_src  = (int*)p;        p += align4(e) * 4;
    ushort_t* W1t     = (ushort_t*)p;   p += (size_t)128 * 512 * 2;
    ushort_t* W2t     = (ushort_t*)p;   p += (size_t)48 * 128 * 2;
    ushort_t* h       = (ushort_t*)p;   p += (size_t)n * 128 * 2;   // h' bf16; g overlays
    ushort_t* h1      = (ushort_t*)p;   p += (size_t)n * 128 * 2;   // bf16
    float*    g       = (float*)h;
    float*    out1    = (float*)d_out;
    float*    out2    = out1 + (size_t)n * 40;

    const int B = 256;
    const int nblkA = (e + 2559) / 2560;

    // CSR build via 2-level counting sort
    hipMemsetAsync(bcnt, 0, (size_t)NB * 4, stream);
    k_bhist<<<nblkA, B, 0, stream>>>(dst, bcnt, e, NB);
    k_bscan<<<1, 256, 0, stream>>>(bcnt, bbase, bcur, row_ptr, NB, n, e);
    k_part<<<nblkA, B, 0, stream>>>(src, dst, bcur, pbuf, e, NB);
    k_bsort<<<NB, 256, 0, stream>>>(pbuf, bbase, cnt, row_ptr, es_src, n);
    k_dinv<<<(n + B - 1) / B, B, 0, stream>>>(cnt, dinv, n);

    // weights
    k_w1t<<<256, 256, 0, stream>>>(W1, W1t);
    k_w2t<<<24, 256, 0, stream>>>(W2, W2t);

    // layer 1
    k_gemm1<<<(n + 63) / 64, 256, 0, stream>>>(x, W1t, dinv, h, n);
    k_agg1<<<(n + 3) / 4, 256, 0, stream>>>((const uint*)h, row_ptr, es_src, dinv, b1, (uint*)h1, n);

    // layer 2
    k_gemm2<<<(n + 63) / 64, 256, 0, stream>>>(h1, W2t, dinv, g, n);
    k_agg2f<<<(n + 5) / 6, 256, 0, stream>>>(g, row_ptr, es_src, dinv, b2, out1, out2, n);
}